// Round 5
// baseline (77.552 us; speedup 1.0000x reference)
//
#include <hip/hip_runtime.h>

// out[b,c] = sum_k w[b,k] * BivariateNormalPDF(X[b,c]; params[b,k])
// B=512, K=64, C=2048.
//
// Round 5: NO LDS, NO barrier, NO in-loop memory.
// K == wavefront size (64): lane l of every wave computes the k=l coefficient
// set once into registers (~30 VALU, redundant per wave, amortized over 64
// k-iters). The k-loop pulls coefficients with v_readlane_b32 (uniform lane
// index = loop counter) -> SGPRs, zero memory latency, waves fully decoupled.
// Inner eval (packed fp32 pairs): dx = x*is1 - m1*is1, dy likewise,
//   e = 2r*dx*dy - (dx*dx + dy*dy);  acc += wn * exp2(e).
// Coefficients: is = sqrt(0.5*log2e/(1-r^2))/s, wn = w/(2pi*s1*s2*sqrt(1-r^2)).

typedef float v2f __attribute__((ext_vector_type(2)));

constexpr int B = 512;
constexpr int K = 64;
constexpr int C = 2048;
constexpr int BLOCK = 256;
constexpr int HALVES = 2;        // each batch's C range split across 2 blocks
constexpr int CH = C / HALVES;   // 1024 points per block -> 4 per thread

__device__ __forceinline__ float rdlane(float v, int k) {
    return __uint_as_float(__builtin_amdgcn_readlane(__float_as_uint(v), k));
}

__global__ __launch_bounds__(BLOCK) void mixture_kernel(
    const float* __restrict__ mo,   // (B, K, 6)
    const float* __restrict__ X,    // (B, C, 2)
    float* __restrict__ out)        // (B, C)
{
    const int bid = blockIdx.x;
    const int b   = bid >> 1;
    const int h   = bid & 1;
    const int t   = threadIdx.x;
    const int lane = t & 63;        // == k index this lane precomputes

    // Issue the X loads first (long-latency), overlap with coefficient math.
    const float4* Xb = (const float4*)(X + (size_t)b * C * 2 + (size_t)h * CH * 2);
    const float4 xv0 = Xb[t];
    const float4 xv1 = Xb[t + BLOCK];

    // Per-lane coefficient set for k = lane (identical in every wave).
    const float* p = mo + ((size_t)(b * K + lane)) * 6;
    const float w  = p[0];
    const float m1 = p[1];
    const float m2 = p[2];
    const float s1 = p[3];
    const float s2 = p[4];
    const float r  = p[5];

    const float omr2 = fmaf(-r, r, 1.0f);
    const float inv  = 1.0f / omr2;
    const float a2   = 0.7213475204444817f * inv;   // 0.5*log2(e)/omr2
    const float sc   = sqrtf(a2);
    const float cIS1 = sc / s1;
    const float cIS2 = sc / s2;
    const float cNM1 = -(m1 * cIS1);
    const float cNM2 = -(m2 * cIS2);
    const float cR2  = 2.0f * r;
    const float cWN  = w * 0.15915494309189535f * sqrtf(inv) / (s1 * s2);

    const v2f xs0 = { xv0.x, xv0.z };
    const v2f ys0 = { xv0.y, xv0.w };
    const v2f xs1 = { xv1.x, xv1.z };
    const v2f ys1 = { xv1.y, xv1.w };
    v2f acc0 = { 0.0f, 0.0f };
    v2f acc1 = { 0.0f, 0.0f };

#pragma unroll 8
    for (int k = 0; k < K; ++k) {
        // Wave-uniform scalar coefficients for this k: pure-register fetch.
        const float fIS1 = rdlane(cIS1, k);
        const float fIS2 = rdlane(cIS2, k);
        const float fNM1 = rdlane(cNM1, k);
        const float fNM2 = rdlane(cNM2, k);
        const float fR2  = rdlane(cR2, k);
        const float fWN  = rdlane(cWN, k);

        const v2f IS1 = { fIS1, fIS1 };
        const v2f IS2 = { fIS2, fIS2 };
        const v2f NM1 = { fNM1, fNM1 };
        const v2f NM2 = { fNM2, fNM2 };
        const v2f R2  = { fR2, fR2 };
        const v2f WN  = { fWN, fWN };

        {
            const v2f dx = __builtin_elementwise_fma(xs0, IS1, NM1);
            const v2f dy = __builtin_elementwise_fma(ys0, IS2, NM2);
            const v2f pq = dx * dy;
            v2f u        = dx * dx;
            u            = __builtin_elementwise_fma(dy, dy, u);
            const v2f e  = __builtin_elementwise_fma(R2, pq, -u);
            v2f ex;
            ex.x = __builtin_amdgcn_exp2f(e.x);
            ex.y = __builtin_amdgcn_exp2f(e.y);
            acc0 = __builtin_elementwise_fma(WN, ex, acc0);
        }
        {
            const v2f dx = __builtin_elementwise_fma(xs1, IS1, NM1);
            const v2f dy = __builtin_elementwise_fma(ys1, IS2, NM2);
            const v2f pq = dx * dy;
            v2f u        = dx * dx;
            u            = __builtin_elementwise_fma(dy, dy, u);
            const v2f e  = __builtin_elementwise_fma(R2, pq, -u);
            v2f ex;
            ex.x = __builtin_amdgcn_exp2f(e.x);
            ex.y = __builtin_amdgcn_exp2f(e.y);
            acc1 = __builtin_elementwise_fma(WN, ex, acc1);
        }
    }

    float2* ob = (float2*)(out + (size_t)b * C + (size_t)h * CH);
    ob[t]         = make_float2(acc0.x, acc0.y);
    ob[t + BLOCK] = make_float2(acc1.x, acc1.y);
}

extern "C" void kernel_launch(void* const* d_in, const int* in_sizes, int n_in,
                              void* d_out, int out_size, void* d_ws, size_t ws_size,
                              hipStream_t stream) {
    const float* mo = (const float*)d_in[0];   // (B,K,6)
    const float* X  = (const float*)d_in[1];   // (B,C,2)
    float* out      = (float*)d_out;           // (B,C)

    mixture_kernel<<<dim3(B * HALVES), dim3(BLOCK), 0, stream>>>(mo, X, out);
}